// Round 14
// baseline (567.431 us; speedup 1.0000x reference)
//
#include <hip/hip_runtime.h>
#include <hip/hip_fp16.h>
#include <math.h>

// GILR model: T=2048 B=32 IN=256 H=512 F=2048 OUT=256
// r14: DIRECT 4-way A/B on gemm2 (one slab each, name-separated):
//   s0 gemm2_a: v3 256x128 BK32 2-buf (256,3)  [ctrl, 70us direct]
//   s1 gemm2_b: kb  256x128 BK64 1-buf, NT=8   [never directly measured]
//   s2 gemm2_c: tlp 128x128 BK32 2-buf (256,4) [4 blk/CU max-TLP]
//   s3 gemm2_d: v3-tile BK32 1-buf 32KB (256,2)[4 blk/CU, no pipeline]
// Rule learned (r12, guide §1): launch_bounds arg2 = min waves/SIMD; >4 forces
// VGPR<=64 (occupancy steps 64/128/256) -> spills. Never exceed 4.
// g1 t2+t3, scan 3-pass, g3 gemm3_k all slabs, prep unchanged.

#define IN_DIM 256
#define H_DIM 512
#define F_DIM 2048
#define OUT_DIM 256

typedef _Float16 f16;
typedef _Float16 f16x8 __attribute__((ext_vector_type(8)));
typedef float f32x4 __attribute__((ext_vector_type(4)));

#define AS3(p) ((__attribute__((address_space(3))) void*)(p))
#define AS1(p) ((const __attribute__((address_space(1))) void*)(p))
#define MFMA16(d, x, y) d = __builtin_amdgcn_mfma_f32_16x16x32_f16(x, y, d, 0, 0, 0)

// ---------------- prep kernels ----------------

__global__ void cvt_kernel(const float* __restrict__ in, f16* __restrict__ out, int n8) {
  int i = blockIdx.x * blockDim.x + threadIdx.x;
  if (i >= n8) return;
  const float4* p = (const float4*)in + (size_t)i * 2;
  float4 a = p[0], b = p[1];
  f16x8 o = { (f16)a.x, (f16)a.y, (f16)a.z, (f16)a.w,
              (f16)b.x, (f16)b.y, (f16)b.z, (f16)b.w };
  *((f16x8*)out + i) = o;
}

__global__ void cvt_w(const float* __restrict__ Wg, const float* __restrict__ Wi,
                      const float* __restrict__ W1, const float* __restrict__ W2,
                      f16* __restrict__ wgi, f16* __restrict__ w1, f16* __restrict__ w2) {
  int i = blockIdx.x * 256 + threadIdx.x;   // 0..229375
  const float* src; f16* dst; int l;
  if (i < 16384)       { l = i;          src = Wg + (size_t)l * 8; dst = wgi + (size_t)l * 8; }
  else if (i < 32768)  { l = i - 16384;  src = Wi + (size_t)l * 8; dst = wgi + 131072 + (size_t)l * 8; }
  else if (i < 163840) { l = i - 32768;  src = W1 + (size_t)l * 8; dst = w1 + (size_t)l * 8; }
  else                 { l = i - 163840; src = W2 + (size_t)l * 8; dst = w2 + (size_t)l * 8; }
  float4 a = ((const float4*)src)[0], b = ((const float4*)src)[1];
  f16x8 o = { (f16)a.x, (f16)a.y, (f16)a.z, (f16)a.w,
              (f16)b.x, (f16)b.y, (f16)b.z, (f16)b.w };
  *(f16x8*)dst = o;
}

__global__ void bias_cat_kernel(const float* __restrict__ bg, const float* __restrict__ bi,
                                float* __restrict__ bgi) {
  int t = threadIdx.x;  // 1024 threads
  bgi[t] = (t < 512) ? bg[t] : bi[t - 512];
}

__device__ __forceinline__ float sigmoid_fast(float v) {
  return __builtin_amdgcn_rcpf(1.0f + __expf(-v));
}
__device__ __forceinline__ float tanh_fast(float v) {
  return 1.0f - 2.0f * __builtin_amdgcn_rcpf(__expf(2.0f * v) + 1.0f);
}
__device__ __forceinline__ float gelu_fast(float v) {
  float u = v * v;
  float y = v * fmaf(0.0713548353f, u, 1.59576912161f);
  return v * __builtin_amdgcn_rcpf(1.0f + __expf(-y));
}

// ---------------- GEMM1 half A: tlp 2-buf (4 blk/CU) ----------------

__global__ __launch_bounds__(256, 4) void gemm1_t2(
    const f16* __restrict__ A, const f16* __restrict__ Bw,
    const float* __restrict__ bias, f16* __restrict__ Cout) {
  constexpr int LDA = 256, LDB = 256, LDC = 1024, NT = 8;
  __shared__ f16 lds[2][2][128][32];   // 32 KiB
  const int tid = threadIdx.x, wid = tid >> 6, lane = tid & 63;
  const int bid = blockIdx.x;
  const int m0 = ((bid & 7) * 32 + (bid >> 6)) * 128;
  const int n0 = ((bid >> 3) & 7) * 128;
  const int wr = (wid >> 1) * 64, wc = (wid & 1) * 64;

  const f16* srcA[2]; const f16* srcB[2];
#pragma unroll
  for (int q = 0; q < 2; ++q) {
    int s = (wid * 2 + q) * 64 + lane;
    int row = s >> 2, g = (s & 3) ^ ((row >> 1) & 3);
    srcA[q] = A + (size_t)(m0 + row) * LDA + g * 8;
    srcB[q] = Bw + (size_t)(n0 + row) * LDB + g * 8;
  }
  auto stage = [&](int buf, int kt) {
    f16* la = &lds[buf][0][0][0] + (wid * 2) * 512;
    f16* lb = &lds[buf][1][0][0] + (wid * 2) * 512;
#pragma unroll
    for (int q = 0; q < 2; ++q) {
      __builtin_amdgcn_global_load_lds(AS1(srcA[q] + kt * 32), AS3(la + q * 512), 16, 0, 0);
      __builtin_amdgcn_global_load_lds(AS1(srcB[q] + kt * 32), AS3(lb + q * 512), 16, 0, 0);
    }
  };
  const int r = lane & 15;
  const int cs = (((lane >> 4) ^ ((lane >> 1) & 3)) << 3);

  f32x4 acc[4][4] = {};
  stage(0, 0);
  for (int kt = 0; kt < NT; ++kt) {
    __syncthreads();
    if (kt + 1 < NT) stage((kt + 1) & 1, kt + 1);
    f16(*At)[32] = lds[kt & 1][0];
    f16(*Bt)[32] = lds[kt & 1][1];
    f16x8 af[4], bf[4];
#pragma unroll
    for (int i = 0; i < 4; ++i) af[i] = *(const f16x8*)&At[wr + i * 16 + r][cs];
#pragma unroll
    for (int i = 0; i < 4; ++i) bf[i] = *(const f16x8*)&Bt[wc + i * 16 + r][cs];
#pragma unroll
    for (int mi = 0; mi < 4; ++mi)
#pragma unroll
      for (int ni = 0; ni < 4; ++ni)
        MFMA16(acc[mi][ni], af[mi], bf[ni]);
  }

  __syncthreads();
  const bool sig = n0 < 512;
  f16* ep = &lds[0][0][0][0] + wid * 4096;   // 64x64 f16
  const int rq = (lane >> 4) * 4;
#pragma unroll
  for (int ni = 0; ni < 4; ++ni) {
    float bv = bias[n0 + wc + ni * 16 + r];
    int cc = ni * 2 + (r >> 3);
#pragma unroll
    for (int mi = 0; mi < 4; ++mi) {
#pragma unroll
      for (int j = 0; j < 4; ++j) {
        int lrow = mi * 16 + rq + j;
        float v = acc[mi][ni][j] + bv;
        float av = sig ? sigmoid_fast(v) : tanh_fast(v);
        ep[lrow * 64 + ((cc ^ (lrow & 7)) << 3) + (r & 7)] = (f16)av;
      }
    }
  }
  asm volatile("s_waitcnt lgkmcnt(0)" ::: "memory");
  __builtin_amdgcn_sched_barrier(0);
#pragma unroll
  for (int t = 0; t < 8; ++t) {
    int idx = t * 64 + lane;
    int row = idx >> 3, c = idx & 7;
    f16x8 v = *(const f16x8*)(ep + row * 64 + ((c ^ (row & 7)) << 3));
    *(f16x8*)(Cout + (size_t)(m0 + wr + row) * LDC + n0 + wc + c * 8) = v;
  }
}

// ---------------- GEMM1 half B: tlp3 (3-buf depth-2 counted) ----------------

__global__ __launch_bounds__(256, 3) void gemm1_t3(
    const f16* __restrict__ A, const f16* __restrict__ Bw,
    const float* __restrict__ bias, f16* __restrict__ Cout) {
  constexpr int LDA = 256, LDB = 256, LDC = 1024, NT = 8;
  __shared__ f16 lds[3][2][128][32];   // 48 KiB
  const int tid = threadIdx.x, wid = tid >> 6, lane = tid & 63;
  const int bid = blockIdx.x;
  const int m0 = ((bid & 7) * 32 + (bid >> 6)) * 128;
  const int n0 = ((bid >> 3) & 7) * 128;
  const int wr = (wid >> 1) * 64, wc = (wid & 1) * 64;

  const f16* srcA[2]; const f16* srcB[2];
#pragma unroll
  for (int q = 0; q < 2; ++q) {
    int s = (wid * 2 + q) * 64 + lane;
    int row = s >> 2, g = (s & 3) ^ ((row >> 1) & 3);
    srcA[q] = A + (size_t)(m0 + row) * LDA + g * 8;
    srcB[q] = Bw + (size_t)(n0 + row) * LDB + g * 8;
  }
  auto stage = [&](int buf, int kt) {
    f16* la = &lds[buf][0][0][0] + (wid * 2) * 512;
    f16* lb = &lds[buf][1][0][0] + (wid * 2) * 512;
#pragma unroll
    for (int q = 0; q < 2; ++q) {
      __builtin_amdgcn_global_load_lds(AS1(srcA[q] + kt * 32), AS3(la + q * 512), 16, 0, 0);
      __builtin_amdgcn_global_load_lds(AS1(srcB[q] + kt * 32), AS3(lb + q * 512), 16, 0, 0);
    }
  };
  const int r = lane & 15;
  const int cs = (((lane >> 4) ^ ((lane >> 1) & 3)) << 3);

  f32x4 acc[4][4] = {};
  stage(0, 0); stage(1, 1);
  asm volatile("s_waitcnt vmcnt(4)" ::: "memory");
  __syncthreads();
#pragma unroll
  for (int kt = 0; kt < NT; ++kt) {
    if (kt + 2 < NT) stage((kt + 2) % 3, kt + 2);
    f16(*At)[32] = lds[kt % 3][0];
    f16(*Bt)[32] = lds[kt % 3][1];
    f16x8 af[4], bf[4];
#pragma unroll
    for (int i = 0; i < 4; ++i) af[i] = *(const f16x8*)&At[wr + i * 16 + r][cs];
#pragma unroll
    for (int i = 0; i < 4; ++i) bf[i] = *(const f16x8*)&Bt[wc + i * 16 + r][cs];
#pragma unroll
    for (int mi = 0; mi < 4; ++mi)
#pragma unroll
      for (int ni = 0; ni < 4; ++ni)
        MFMA16(acc[mi][ni], af[mi], bf[ni]);
    if (kt + 1 < NT) {
      if (kt + 2 < NT) asm volatile("s_waitcnt vmcnt(4)" ::: "memory");
      else             asm volatile("s_waitcnt vmcnt(0)" ::: "memory");
      __syncthreads();
    }
  }

  __syncthreads();
  const bool sig = n0 < 512;
  f16* ep = &lds[0][0][0][0] + wid * 4096;
  const int rq = (lane >> 4) * 4;
#pragma unroll
  for (int ni = 0; ni < 4; ++ni) {
    float bv = bias[n0 + wc + ni * 16 + r];
    int cc = ni * 2 + (r >> 3);
#pragma unroll
    for (int mi = 0; mi < 4; ++mi) {
#pragma unroll
      for (int j = 0; j < 4; ++j) {
        int lrow = mi * 16 + rq + j;
        float v = acc[mi][ni][j] + bv;
        float av = sig ? sigmoid_fast(v) : tanh_fast(v);
        ep[lrow * 64 + ((cc ^ (lrow & 7)) << 3) + (r & 7)] = (f16)av;
      }
    }
  }
  asm volatile("s_waitcnt lgkmcnt(0)" ::: "memory");
  __builtin_amdgcn_sched_barrier(0);
#pragma unroll
  for (int t = 0; t < 8; ++t) {
    int idx = t * 64 + lane;
    int row = idx >> 3, c = idx & 7;
    f16x8 v = *(const f16x8*)(ep + row * 64 + ((c ^ (row & 7)) << 3));
    *(f16x8*)(Cout + (size_t)(m0 + wr + row) * LDC + n0 + wc + c * 8) = v;
  }
}

// ============ GEMM2 variant a: v3 256x128 BK32 2-buf (256,3) — control ============

__global__ __launch_bounds__(256, 3) void gemm2_a(
    const f16* __restrict__ A, const f16* __restrict__ Bw,
    const float* __restrict__ bias, f16* __restrict__ Cout) {
  constexpr int LDA = 1024, LDB = 512, LDC = 2048, NT = 16;
  __shared__ f16 lds[24576];   // 48 KiB
  const int tid = threadIdx.x, wid = tid >> 6, lane = tid & 63;
  const int lr = lane & 15;
  const int bid = blockIdx.x;
  const int m0 = ((bid & 7) * 8 + (bid >> 7)) * 256;
  const int n0 = ((bid >> 3) & 15) * 128;
  const int wr = (wid >> 1) * 128, wc = (wid & 1) * 64;

  const f16* srcA[4];
  const f16* srcB[2];
#pragma unroll
  for (int q = 0; q < 4; ++q) {
    int s = wid * 256 + q * 64 + lane;
    int row = s >> 2, g = (s & 3) ^ ((row >> 1) & 3);
    srcA[q] = A + (size_t)(m0 + row) * LDA + g * 8;
  }
#pragma unroll
  for (int q = 0; q < 2; ++q) {
    int s = wid * 128 + q * 64 + lane;
    int row = s >> 2, g = (s & 3) ^ ((row >> 1) & 3);
    srcB[q] = Bw + (size_t)(n0 + row) * LDB + g * 8;
  }
  auto stage = [&](int buf, int kt) {
#pragma unroll
    for (int q = 0; q < 4; ++q)
      __builtin_amdgcn_global_load_lds(AS1(srcA[q] + kt * 32),
          AS3(lds + buf * 8192 + wid * 2048 + q * 512), 16, 0, 0);
#pragma unroll
    for (int q = 0; q < 2; ++q)
      __builtin_amdgcn_global_load_lds(AS1(srcB[q] + kt * 32),
          AS3(lds + 16384 + buf * 4096 + wid * 1024 + q * 512), 16, 0, 0);
  };

  const int qsf = (((lane >> 4) ^ ((lr >> 1) & 3)) << 3);
  f32x4 acc[8][4] = {};
  stage(0, 0);
  for (int kt = 0; kt < NT; ++kt) {
    const int cur = kt & 1;
    __syncthreads();
    if (kt + 1 < NT) stage(cur ^ 1, kt + 1);
    f16x8 af[8], bf[4];
#pragma unroll
    for (int mi = 0; mi < 8; ++mi)
      af[mi] = *(const f16x8*)(lds + cur * 8192 + (wr + mi * 16 + lr) * 32 + qsf);
#pragma unroll
    for (int ni = 0; ni < 4; ++ni)
      bf[ni] = *(const f16x8*)(lds + 16384 + cur * 4096 + (wc + ni * 16 + lr) * 32 + qsf);
#pragma unroll
    for (int mi = 0; mi < 8; ++mi)
#pragma unroll
      for (int ni = 0; ni < 4; ++ni)
        MFMA16(acc[mi][ni], af[mi], bf[ni]);
  }

  __syncthreads();
  f16* ep = lds + wid * 4096;
  const int rq = (lane >> 4) * 4;
#pragma unroll
  for (int h = 0; h < 2; ++h) {
#pragma unroll
    for (int mi = 0; mi < 4; ++mi) {
#pragma unroll
      for (int ni = 0; ni < 4; ++ni) {
        float bv = bias[n0 + wc + ni * 16 + lr];
        int cc = ni * 2 + (lr >> 3);
#pragma unroll
        for (int j = 0; j < 4; ++j) {
          int lrow = mi * 16 + rq + j;
          float v = gelu_fast(acc[h * 4 + mi][ni][j] + bv);
          ep[lrow * 64 + ((cc ^ (lrow & 7)) << 3) + (lr & 7)] = (f16)v;
        }
      }
    }
    asm volatile("s_waitcnt lgkmcnt(0)" ::: "memory");
    __builtin_amdgcn_sched_barrier(0);
#pragma unroll
    for (int t = 0; t < 8; ++t) {
      int idx = t * 64 + lane;
      int row = idx >> 3, c = idx & 7;
      f16x8 v = *(const f16x8*)(ep + row * 64 + ((c ^ (row & 7)) << 3));
      *(f16x8*)(Cout + (size_t)(m0 + wr + h * 64 + row) * LDC + n0 + wc + c * 8) = v;
    }
    asm volatile("s_waitcnt lgkmcnt(0)" ::: "memory");
    __builtin_amdgcn_sched_barrier(0);
  }
}

// ============ GEMM2 variant b: kb 256x128 BK64 single-buffer, NT=8 ============

__global__ __launch_bounds__(256, 2) void gemm2_b(
    const f16* __restrict__ A, const f16* __restrict__ Bw,
    const float* __restrict__ bias, f16* __restrict__ Cout) {
  constexpr int LDA = 1024, LDB = 512, LDC = 2048, NT = 8;
  __shared__ f16 lds[24576];   // A: row*64 (32KB) ; B: 16384 + row*64 (16KB)
  const int tid = threadIdx.x, wid = tid >> 6, lane = tid & 63;
  const int lr = lane & 15;
  const int bid = blockIdx.x;
  const int m0 = ((bid & 7) * 8 + (bid >> 7)) * 256;
  const int n0 = ((bid >> 3) & 15) * 128;
  const int wr = (wid >> 1) * 128, wc = (wid & 1) * 64;

  const f16* srcA[8];
  const f16* srcB[4];
#pragma unroll
  for (int q = 0; q < 8; ++q) {
    int s = wid * 512 + q * 64 + lane;
    int row = s >> 3, g = (s & 7) ^ (row & 7);
    srcA[q] = A + (size_t)(m0 + row) * LDA + g * 8;
  }
#pragma unroll
  for (int q = 0; q < 4; ++q) {
    int s = wid * 256 + q * 64 + lane;
    int row = s >> 3, g = (s & 7) ^ (row & 7);
    srcB[q] = Bw + (size_t)(n0 + row) * LDB + g * 8;
  }
  auto stage = [&](int kt) {
#pragma unroll
    for (int q = 0; q < 8; ++q)
      __builtin_amdgcn_global_load_lds(AS1(srcA[q] + kt * 64),
          AS3(lds + wid * 4096 + q * 512), 16, 0, 0);
#pragma unroll
    for (int q = 0; q < 4; ++q)
      __builtin_amdgcn_global_load_lds(AS1(srcB[q] + kt * 64),
          AS3(lds + 16384 + wid * 2048 + q * 512), 16, 0, 0);
  };

  const int qs0 = (((lane >> 4) ^ (lr & 7)) << 3);
  const int qs1 = (((4 + (lane >> 4)) ^ (lr & 7)) << 3);
  f32x4 acc[8][4] = {};
  for (int kt = 0; kt < NT; ++kt) {
    stage(kt);
    __syncthreads();   // staged (barrier drains vmcnt)
#pragma unroll
    for (int kk = 0; kk < 2; ++kk) {
      const int qs = kk ? qs1 : qs0;
      f16x8 af[8], bf[4];
#pragma unroll
      for (int mi = 0; mi < 8; ++mi)
        af[mi] = *(const f16x8*)(lds + (wr + mi * 16 + lr) * 64 + qs);
#pragma unroll
      for (int ni = 0; ni < 4; ++ni)
        bf[ni] = *(const f16x8*)(lds + 16384 + (wc + ni * 16 + lr) * 64 + qs);
#pragma unroll
      for (int mi = 0; mi < 8; ++mi)
#pragma unroll
        for (int ni = 0; ni < 4; ++ni)
          MFMA16(acc[mi][ni], af[mi], bf[ni]);
    }
    __syncthreads();   // reads done before next stage overwrites
  }

  f16* ep = lds + wid * 4096;
  const int rq = (lane >> 4) * 4;
#pragma unroll
  for (int h = 0; h < 2; ++h) {
#pragma unroll
    for (int mi = 0; mi < 4; ++mi) {
#pragma unroll
      for (int ni = 0; ni < 4; ++ni) {
        float bv = bias[n0 + wc + ni * 16 + lr];
        int cc = ni * 2 + (lr >> 3);
#pragma unroll
        for (int j = 0; j < 4; ++j) {
          int lrow = mi * 16 + rq + j;
          float v = gelu_fast(acc[h * 4 + mi][ni][j] + bv);
          ep[lrow * 64 + ((cc ^ (lrow & 7)) << 3) + (lr & 7)] = (f16)v;
        }
      }
    }
    asm volatile("s_waitcnt lgkmcnt(0)" ::: "memory");
    __builtin_amdgcn_sched_barrier(0);
#pragma unroll
    for (int t = 0; t < 8; ++t) {
      int idx = t * 64 + lane;
      int row = idx >> 3, c = idx & 7;
      f16x8 v = *(const f16x8*)(ep + row * 64 + ((c ^ (row & 7)) << 3));
      *(f16x8*)(Cout + (size_t)(m0 + wr + h * 64 + row) * LDC + n0 + wc + c * 8) = v;
    }
    asm volatile("s_waitcnt lgkmcnt(0)" ::: "memory");
    __builtin_amdgcn_sched_barrier(0);
  }
}

// ============ GEMM2 variant c: tlp 128x128 BK32 2-buf (256,4) — 4 blk/CU ============

__global__ __launch_bounds__(256, 4) void gemm2_c(
    const f16* __restrict__ A, const f16* __restrict__ Bw,
    const float* __restrict__ bias, f16* __restrict__ Cout) {
  constexpr int LDA = 1024, LDB = 512, LDC = 2048, NT = 16;
  __shared__ f16 lds[2][2][128][32];   // 32 KiB
  const int tid = threadIdx.x, wid = tid >> 6, lane = tid & 63;
  const int bid = blockIdx.x;  // 2048 = 8 xcd x 16 n x 16 m
  const int m0 = ((bid & 7) * 16 + (bid >> 7)) * 128;
  const int n0 = ((bid >> 3) & 15) * 128;
  const int wr = (wid >> 1) * 64, wc = (wid & 1) * 64;

  const f16* srcA[2]; const f16* srcB[2];
#pragma unroll
  for (int q = 0; q < 2; ++q) {
    int s = (wid * 2 + q) * 64 + lane;
    int row = s >> 2, g = (s & 3) ^ ((row >> 1) & 3);
    srcA[q] = A + (size_t)(m0 + row) * LDA + g * 8;
    srcB[q] = Bw + (size_t)(n0 + row) * LDB + g * 8;
  }
  auto stage = [&](int buf, int kt) {
    f16* la = &lds[buf][0][0][0] + (wid * 2) * 512;
    f16* lb = &lds[buf][1][0][0] + (wid * 2) * 512;
#pragma unroll
    for (int q = 0; q < 2; ++q) {
      __builtin_amdgcn_global_load_lds(AS1(srcA[q] + kt * 32), AS3(la + q * 512), 16, 0, 0);
      __builtin_amdgcn_global_load_lds(AS1(srcB[q] + kt * 32), AS3(lb + q * 512), 16, 0, 0);
    }
  };
  const int r = lane & 15;
  const int cs = (((lane >> 4) ^ ((lane >> 1) & 3)) << 3);

  f32x4 acc[4][4] = {};
  stage(0, 0);
  for (int kt = 0; kt < NT; ++kt) {
    __syncthreads();
    if (kt + 1 < NT) stage((kt + 1) & 1, kt + 1);
    f16(*At)[32] = lds[kt & 1][0];
    f16(*Bt)[32] = lds[kt & 1][1];
    f16x8 af[4], bf[4];
#pragma unroll
    for (int i = 0; i < 4; ++i) af[i] = *(const f16x8*)&At[wr + i * 16 + r][cs];
#pragma unroll
    for (int i = 0; i < 4; ++i) bf[i] = *(const f16x8*)&Bt[wc + i * 16 + r][cs];
#pragma unroll
    for (int mi = 0; mi < 4; ++mi)
#pragma unroll
      for (int ni = 0; ni < 4; ++ni)
        MFMA16(acc[mi][ni], af[mi], bf[ni]);
  }

  __syncthreads();
  f16* ep = &lds[0][0][0][0] + wid * 4096;   // 64x64 f16
  const int rq = (lane >> 4) * 4;
#pragma unroll
  for (int ni = 0; ni < 4; ++ni) {
    float bv = bias[n0 + wc + ni * 16 + r];
    int cc = ni * 2 + (r >> 3);
#pragma unroll
    for (int mi = 0; mi < 4; ++mi) {
#pragma unroll
      for (int j = 0; j < 4; ++j) {
        int lrow = mi * 16 + rq + j;
        float v = gelu_fast(acc[mi][ni][j] + bv);
        ep[lrow * 64 + ((cc ^ (lrow & 7)) << 3) + (r & 7)] = (f16)v;
      }
    }
  }
  asm volatile("s_waitcnt lgkmcnt(0)" ::: "memory");
  __builtin_amdgcn_sched_barrier(0);
#pragma unroll
  for (int t = 0; t < 8; ++t) {
    int idx = t * 64 + lane;
    int row = idx >> 3, c = idx & 7;
    f16x8 v = *(const f16x8*)(ep + row * 64 + ((c ^ (row & 7)) << 3));
    *(f16x8*)(Cout + (size_t)(m0 + wr + row) * LDC + n0 + wc + c * 8) = v;
  }
}

// ============ GEMM2 variant d: v3-tile BK32 single-buffer 32KB — 4 blk/CU ============

__global__ __launch_bounds__(256, 2) void gemm2_d(
    const f16* __restrict__ A, const f16* __restrict__ Bw,
    const float* __restrict__ bias, f16* __restrict__ Cout) {
  constexpr int LDA = 1024, LDB = 512, LDC = 2048, NT = 16;
  __shared__ f16 lds[16384];   // 32 KiB: A row*32 (16KB), B at 8192 f16 (8KB); epi 32KB
  const int tid = threadIdx.x, wid = tid >> 6, lane = tid & 63;
  const int lr = lane & 15;
  const int bid = blockIdx.x;
  const int m0 = ((bid & 7) * 8 + (bid >> 7)) * 256;
  const int n0 = ((bid >> 3) & 15) * 128;
  const int wr = (wid >> 1) * 128, wc = (wid & 1) * 64;

  const f16* srcA[4];
  const f16* srcB[2];
#pragma unroll
  for (int q = 0; q < 4; ++q) {
    int s = wid * 256 + q * 64 + lane;
    int row = s >> 2, g = (s & 3) ^ ((row >> 1) & 3);
    srcA[q] = A + (size_t)(m0 + row) * LDA + g * 8;
  }
#pragma unroll
  for (int q = 0; q < 2; ++q) {
    int s = wid * 128 + q * 64 + lane;
    int row = s >> 2, g = (s & 3) ^ ((row >> 1) & 3);
    srcB[q] = Bw + (size_t)(n0 + row) * LDB + g * 8;
  }
  auto stage = [&](int kt) {
#pragma unroll
    for (int q = 0; q < 4; ++q)
      __builtin_amdgcn_global_load_lds(AS1(srcA[q] + kt * 32),
          AS3(lds + wid * 2048 + q * 512), 16, 0, 0);
#pragma unroll
    for (int q = 0; q < 2; ++q)
      __builtin_amdgcn_global_load_lds(AS1(srcB[q] + kt * 32),
          AS3(lds + 8192 + wid * 1024 + q * 512), 16, 0, 0);
  };

  const int qsf = (((lane >> 4) ^ ((lr >> 1) & 3)) << 3);
  f32x4 acc[8][4] = {};
  for (int kt = 0; kt < NT; ++kt) {
    stage(kt);
    __syncthreads();   // staged visible (barrier drains vmcnt)
    f16x8 af[8], bf[4];
#pragma unroll
    for (int mi = 0; mi < 8; ++mi)
      af[mi] = *(const f16x8*)(lds + (wr + mi * 16 + lr) * 32 + qsf);
#pragma unroll
    for (int ni = 0; ni < 4; ++ni)
      bf[ni] = *(const f16x8*)(lds + 8192 + (wc + ni * 16 + lr) * 32 + qsf);
#pragma unroll
    for (int mi = 0; mi < 8; ++mi)
#pragma unroll
      for (int ni = 0; ni < 4; ++ni)
        MFMA16(acc[mi][ni], af[mi], bf[ni]);
    __syncthreads();   // reads done before next stage overwrites
  }

  f16* ep = lds + wid * 4096;
  const int rq = (lane >> 4) * 4;
#pragma unroll
  for (int h = 0; h < 2; ++h) {
#pragma unroll
    for (int mi = 0; mi < 4; ++mi) {
#pragma unroll
      for (int ni = 0; ni < 4; ++ni) {
        float bv = bias[n0 + wc + ni * 16 + lr];
        int cc = ni * 2 + (lr >> 3);
#pragma unroll
        for (int j = 0; j < 4; ++j) {
          int lrow = mi * 16 + rq + j;
          float v = gelu_fast(acc[h * 4 + mi][ni][j] + bv);
          ep[lrow * 64 + ((cc ^ (lrow & 7)) << 3) + (lr & 7)] = (f16)v;
        }
      }
    }
    asm volatile("s_waitcnt lgkmcnt(0)" ::: "memory");
    __builtin_amdgcn_sched_barrier(0);
#pragma unroll
    for (int t = 0; t < 8; ++t) {
      int idx = t * 64 + lane;
      int row = idx >> 3, c = idx & 7;
      f16x8 v = *(const f16x8*)(ep + row * 64 + ((c ^ (row & 7)) << 3));
      *(f16x8*)(Cout + (size_t)(m0 + wr + h * 64 + row) * LDC + n0 + wc + c * 8) = v;
    }
    asm volatile("s_waitcnt lgkmcnt(0)" ::: "memory");
    __builtin_amdgcn_sched_barrier(0);
  }
}

// ---------------- GEMM3 (m97 128x128): z@W2^T + b2 -> f32 ----------------

__global__ __launch_bounds__(256, 2) void gemm3_k(
    const f16* __restrict__ A, const f16* __restrict__ Bw,
    const float* __restrict__ bias, float* __restrict__ Cout) {
  constexpr int LDA = 2048, LDB = 2048, LDC = 256, NT = 32;
  __shared__ f16 lds[2][2][128][64];
  const int tid = threadIdx.x, wid = tid >> 6, lane = tid & 63;
  const int bid = blockIdx.x;
  const int m0 = ((bid & 7) * 16 + (bid >> 4)) * 128;
  const int n0 = ((bid >> 3) & 1) * 128;
  const int wr = (wid >> 1) * 64, wc = (wid & 1) * 64;

  auto stage = [&](int buf, int kt) {
    const f16* ga = A + (size_t)m0 * LDA + kt * 64;
    const f16* gb = Bw + (size_t)n0 * LDB + kt * 64;
    f16* la = &lds[buf][0][0][0];
    f16* lb = &lds[buf][1][0][0];
#pragma unroll
    for (int q = 0; q < 4; ++q) {
      int seg = (wid << 2) + q;
      int s = seg * 64 + lane;
      int row = s >> 3, col = (s & 7) << 3;
      __builtin_amdgcn_global_load_lds(AS1(ga + (size_t)row * LDA + col),
                                       AS3(la + seg * 512), 16, 0, 0);
      __builtin_amdgcn_global_load_lds(AS1(gb + (size_t)row * LDB + col),
                                       AS3(lb + seg * 512), 16, 0, 0);
    }
  };

  f32x4 acc[4][4] = {};
  stage(0, 0);
  for (int kt = 0; kt < NT; ++kt) {
    __syncthreads();
    if (kt + 1 < NT) stage((kt + 1) & 1, kt + 1);
    f16(*At)[64] = lds[kt & 1][0];
    f16(*Bt)[64] = lds[kt & 1][1];
    const int r = lane & 15, cg = (lane >> 4) << 3;
#pragma unroll
    for (int kk = 0; kk < 2; ++kk) {
      f16x8 af[4], bf[4];
#pragma unroll
      for (int i = 0; i < 4; ++i)
        af[i] = *(const f16x8*)&At[wr + i * 16 + r][kk * 32 + cg];
#pragma unroll
      for (int i = 0; i < 4; ++i)
        bf[i] = *(const f16x8*)&Bt[wc + i * 16 + r][kk * 32 + cg];
#pragma unroll
      for (int mi = 0; mi < 4; ++mi)
#pragma unroll
        for (int ni = 0; ni < 4; ++ni)
          MFMA16(acc[mi][ni], af[mi], bf[ni]);
    }
  }
  const int r = lane & 15, rq = (lane >> 4) * 4;
#pragma unroll
  for (int ni = 0; ni < 4; ++ni) {
    int col = n0 + wc + ni * 16 + r;
    float bv = bias[col];
#pragma unroll
    for (int mi = 0; mi < 4; ++mi) {
#pragma unroll
      for (int j = 0; j < 4; ++j) {
        int row = m0 + wr + mi * 16 + rq + j;
        Cout[(size_t)row * LDC + col] = acc[mi][ni][j] + bv;
      }
    }
  }
}

// ---------------- scan (3-pass, gates pre-activated; HBM roofline) ----------------

#define NCH 16384
#define NCHUNK 32
#define CLEN 64

__global__ void scan_p1(const f16* __restrict__ ab, float* __restrict__ cA,
                        float* __restrict__ cH) {
  int ch = blockIdx.x * 256 + threadIdx.x;
  int c = blockIdx.y;
  const f16* pg = ab + (size_t)(c * CLEN) * 32768 + (ch >> 9) * 1024 + (ch & 511);
  const f16* pi = pg + 512;
  float A = 1.f, Hl = 0.f;
  for (int t = 0; t < CLEN; ++t) {
    float g = (float)pg[0];
    float ii = (float)pi[0];
    Hl = fmaf(g, Hl - ii, ii);
    A *= g;
    pg += 32768; pi += 32768;
  }
  cA[c * NCH + ch] = A;
  cH[c * NCH + ch] = Hl;
}

__global__ void scan_p2(const float* __restrict__ cA, const float* __restrict__ cH,
                        float* __restrict__ st) {
  int ch = blockIdx.x * 256 + threadIdx.x;
  float h0 = 0.f;
  for (int c = 0; c < NCHUNK; ++c) {
    st[c * NCH + ch] = h0;
    h0 = cA[c * NCH + ch] * h0 + cH[c * NCH + ch];
  }
}

__global__ void scan_p3(f16* __restrict__ ab, const float* __restrict__ st) {
  int ch = blockIdx.x * 256 + threadIdx.x;
  int c = blockIdx.y;
  f16* pg = ab + (size_t)(c * CLEN) * 32768 + (ch >> 9) * 1024 + (ch & 511);
  const f16* pi = pg + 512;
  float hv = st[c * NCH + ch];
  for (int t = 0; t < CLEN; ++t) {
    float g = (float)pg[0];
    float ii = (float)pi[0];
    hv = fmaf(g, hv - ii, ii);
    pg[0] = (f16)hv;
    pg += 32768; pi += 32768;
  }
}

// ---------------- launch ----------------

extern "C" void kernel_launch(void* const* d_in, const int* in_sizes, int n_in,
                              void* d_out, int out_size, void* d_ws, size_t ws_size,
                              hipStream_t stream) {
  const float* x  = (const float*)d_in[0];
  const float* Wg = (const float*)d_in[1];
  const float* bg = (const float*)d_in[2];
  const float* Wi = (const float*)d_in[3];
  const float* bi = (const float*)d_in[4];
  const float* W1 = (const float*)d_in[5];
  const float* b1 = (const float*)d_in[6];
  const float* W2 = (const float*)d_in[7];
  const float* b2 = (const float*)d_in[8];
  float* out = (float*)d_out;

  char* ws = (char*)d_ws;
  f16*   wgi16 = (f16*)(ws + 0);            // 1024x256 f16
  f16*   w116  = (f16*)(ws + 524288);       // 2048x512 f16
  f16*   w216  = (f16*)(ws + 2621440);      // 256x2048 f16
  float* bgi   = (float*)(ws + 3670016);    // 1024 f32
  f16*   x16   = (f16*)(ws + 4194304);      // 65536x256 f16
  f16*   ab16  = (f16*)(ws + 37748736);     // 65536x1024 f16 (g|i, then h|i)
  float* cA    = (float*)(ws + 171966464);  // 32x16384 f32
  float* cH    = (float*)(ws + 174063616);
  float* st    = (float*)(ws + 176160768);
  f16*   z16   = (f16*)(ws + 178257920);    // 16384x2048 f16
  if (ws_size < 245366784) return;

  // prep
  cvt_w<<<896, 256, 0, stream>>>(Wg, Wi, W1, W2, wgi16, w116, w216);
  bias_cat_kernel<<<1, 1024, 0, stream>>>(bg, bi, bgi);
  cvt_kernel<<<8192, 256, 0, stream>>>(x, x16, 2097152);

  // GEMM1 halves
  gemm1_t2<<<2048, 256, 0, stream>>>(x16, wgi16, bgi, ab16);
  gemm1_t3<<<2048, 256, 0, stream>>>(x16 + (size_t)32768 * 256, wgi16, bgi,
                                     ab16 + (size_t)32768 * 1024);

  // scan
  scan_p1<<<dim3(64, NCHUNK), 256, 0, stream>>>(ab16, cA, cH);
  scan_p2<<<64, 256, 0, stream>>>(cA, cH, st);
  scan_p3<<<dim3(64, NCHUNK), 256, 0, stream>>>(ab16, st);

  // 4 T-slabs: GEMM2 4-way A/B (a/b/c/d, one slab each) ; GEMM3 ctrl
  for (int s = 0; s < 4; ++s) {
    const f16* hs = ab16 + (size_t)s * 16384 * 1024;
    if (s == 0)      gemm2_a<<<1024, 256, 0, stream>>>(hs, w116, b1, z16);
    else if (s == 1) gemm2_b<<<1024, 256, 0, stream>>>(hs, w116, b1, z16);
    else if (s == 2) gemm2_c<<<2048, 256, 0, stream>>>(hs, w116, b1, z16);
    else             gemm2_d<<<1024, 256, 0, stream>>>(hs, w116, b1, z16);
    gemm3_k<<<256, 256, 0, stream>>>(z16, w216, b2, out + (size_t)s * 16384 * 256);
  }
}

// Round 15
// 474.123 us; speedup vs baseline: 1.1968x; 1.1968x over previous
//
#include <hip/hip_runtime.h>
#include <hip/hip_fp16.h>
#include <math.h>

// GILR model: T=2048 B=32 IN=256 H=512 F=2048 OUT=256
// r15 consolidation: both occupancy wins adopted, no experiments.
//   g2: 4x gemm2_a (v3 256x128 BK32 2-buf, (256,3) = 3 blk/CU) — family optimum;
//       all schedule variants (a/b/c/d/q/qq/f/8p) land 70-91, structure-independent.
//   g3: 4x gemm3_h (128x64, grid 512 = 2 blk/CU) — r13<->r14 ledger algebra winner
//       (~20-30us/slab faster than 1-blk/CU gemm3_k; same mechanism as k3>k2).
//   g1 t2+t3 halves, scan 3-pass (roofline), prep unchanged.
// Ledger rules learned: top-5 = WORST replays (upper bounds); never infer via
// residuals; launch_bounds arg2 = waves/SIMD (>4 forces VGPR<=64 -> spill).

#define IN_DIM 256
#define H_DIM 512
#define F_DIM 2048
#define OUT_DIM 256

typedef _Float16 f16;
typedef _Float16 f16x8 __attribute__((ext_vector_type(8)));
typedef float f32x4 __attribute__((ext_vector_type(4)));

#define AS3(p) ((__attribute__((address_space(3))) void*)(p))
#define AS1(p) ((const __attribute__((address_space(1))) void*)(p))
#define MFMA16(d, x, y) d = __builtin_amdgcn_mfma_f32_16x16x32_f16(x, y, d, 0, 0, 0)

// ---------------- prep kernels ----------------

__global__ void cvt_kernel(const float* __restrict__ in, f16* __restrict__ out, int n8) {
  int i = blockIdx.x * blockDim.x + threadIdx.x;
  if (i >= n8) return;
  const float4* p = (const float4*)in + (size_t)i * 2;
  float4 a = p[0], b = p[1];
  f16x8 o = { (f16)a.x, (f16)a.y, (f16)a.z, (f16)a.w,
              (f16)b.x, (f16)b.y, (f16)b.z, (f16)b.w };
  *((f16x8*)out + i) = o;
}

__global__ void cvt_w(const float* __restrict__ Wg, const float* __restrict__ Wi,
                      const float* __restrict__ W1, const float* __restrict__ W2,
                      f16* __restrict__ wgi, f16* __restrict__ w1, f16* __restrict__ w2) {
  int i = blockIdx.x * 256 + threadIdx.x;   // 0..229375
  const float* src; f16* dst; int l;
  if (i < 16384)       { l = i;          src = Wg + (size_t)l * 8; dst = wgi + (size_t)l * 8; }
  else if (i < 32768)  { l = i - 16384;  src = Wi + (size_t)l * 8; dst = wgi + 131072 + (size_t)l * 8; }
  else if (i < 163840) { l = i - 32768;  src = W1 + (size_t)l * 8; dst = w1 + (size_t)l * 8; }
  else                 { l = i - 163840; src = W2 + (size_t)l * 8; dst = w2 + (size_t)l * 8; }
  float4 a = ((const float4*)src)[0], b = ((const float4*)src)[1];
  f16x8 o = { (f16)a.x, (f16)a.y, (f16)a.z, (f16)a.w,
              (f16)b.x, (f16)b.y, (f16)b.z, (f16)b.w };
  *(f16x8*)dst = o;
}

__global__ void bias_cat_kernel(const float* __restrict__ bg, const float* __restrict__ bi,
                                float* __restrict__ bgi) {
  int t = threadIdx.x;  // 1024 threads
  bgi[t] = (t < 512) ? bg[t] : bi[t - 512];
}

__device__ __forceinline__ float sigmoid_fast(float v) {
  return __builtin_amdgcn_rcpf(1.0f + __expf(-v));
}
__device__ __forceinline__ float tanh_fast(float v) {
  return 1.0f - 2.0f * __builtin_amdgcn_rcpf(__expf(2.0f * v) + 1.0f);
}
__device__ __forceinline__ float gelu_fast(float v) {
  float u = v * v;
  float y = v * fmaf(0.0713548353f, u, 1.59576912161f);
  return v * __builtin_amdgcn_rcpf(1.0f + __expf(-y));
}

// ---------------- GEMM1 half A: tlp 2-buf (4 blk/CU) ----------------

__global__ __launch_bounds__(256, 4) void gemm1_t2(
    const f16* __restrict__ A, const f16* __restrict__ Bw,
    const float* __restrict__ bias, f16* __restrict__ Cout) {
  constexpr int LDA = 256, LDB = 256, LDC = 1024, NT = 8;
  __shared__ f16 lds[2][2][128][32];   // 32 KiB
  const int tid = threadIdx.x, wid = tid >> 6, lane = tid & 63;
  const int bid = blockIdx.x;
  const int m0 = ((bid & 7) * 32 + (bid >> 6)) * 128;
  const int n0 = ((bid >> 3) & 7) * 128;
  const int wr = (wid >> 1) * 64, wc = (wid & 1) * 64;

  const f16* srcA[2]; const f16* srcB[2];
#pragma unroll
  for (int q = 0; q < 2; ++q) {
    int s = (wid * 2 + q) * 64 + lane;
    int row = s >> 2, g = (s & 3) ^ ((row >> 1) & 3);
    srcA[q] = A + (size_t)(m0 + row) * LDA + g * 8;
    srcB[q] = Bw + (size_t)(n0 + row) * LDB + g * 8;
  }
  auto stage = [&](int buf, int kt) {
    f16* la = &lds[buf][0][0][0] + (wid * 2) * 512;
    f16* lb = &lds[buf][1][0][0] + (wid * 2) * 512;
#pragma unroll
    for (int q = 0; q < 2; ++q) {
      __builtin_amdgcn_global_load_lds(AS1(srcA[q] + kt * 32), AS3(la + q * 512), 16, 0, 0);
      __builtin_amdgcn_global_load_lds(AS1(srcB[q] + kt * 32), AS3(lb + q * 512), 16, 0, 0);
    }
  };
  const int r = lane & 15;
  const int cs = (((lane >> 4) ^ ((lane >> 1) & 3)) << 3);

  f32x4 acc[4][4] = {};
  stage(0, 0);
  for (int kt = 0; kt < NT; ++kt) {
    __syncthreads();
    if (kt + 1 < NT) stage((kt + 1) & 1, kt + 1);
    f16(*At)[32] = lds[kt & 1][0];
    f16(*Bt)[32] = lds[kt & 1][1];
    f16x8 af[4], bf[4];
#pragma unroll
    for (int i = 0; i < 4; ++i) af[i] = *(const f16x8*)&At[wr + i * 16 + r][cs];
#pragma unroll
    for (int i = 0; i < 4; ++i) bf[i] = *(const f16x8*)&Bt[wc + i * 16 + r][cs];
#pragma unroll
    for (int mi = 0; mi < 4; ++mi)
#pragma unroll
      for (int ni = 0; ni < 4; ++ni)
        MFMA16(acc[mi][ni], af[mi], bf[ni]);
  }

  __syncthreads();
  const bool sig = n0 < 512;
  f16* ep = &lds[0][0][0][0] + wid * 4096;   // 64x64 f16
  const int rq = (lane >> 4) * 4;
#pragma unroll
  for (int ni = 0; ni < 4; ++ni) {
    float bv = bias[n0 + wc + ni * 16 + r];
    int cc = ni * 2 + (r >> 3);
#pragma unroll
    for (int mi = 0; mi < 4; ++mi) {
#pragma unroll
      for (int j = 0; j < 4; ++j) {
        int lrow = mi * 16 + rq + j;
        float v = acc[mi][ni][j] + bv;
        float av = sig ? sigmoid_fast(v) : tanh_fast(v);
        ep[lrow * 64 + ((cc ^ (lrow & 7)) << 3) + (r & 7)] = (f16)av;
      }
    }
  }
  asm volatile("s_waitcnt lgkmcnt(0)" ::: "memory");
  __builtin_amdgcn_sched_barrier(0);
#pragma unroll
  for (int t = 0; t < 8; ++t) {
    int idx = t * 64 + lane;
    int row = idx >> 3, c = idx & 7;
    f16x8 v = *(const f16x8*)(ep + row * 64 + ((c ^ (row & 7)) << 3));
    *(f16x8*)(Cout + (size_t)(m0 + wr + row) * LDC + n0 + wc + c * 8) = v;
  }
}

// ---------------- GEMM1 half B: tlp3 (3-buf depth-2 counted) ----------------

__global__ __launch_bounds__(256, 3) void gemm1_t3(
    const f16* __restrict__ A, const f16* __restrict__ Bw,
    const float* __restrict__ bias, f16* __restrict__ Cout) {
  constexpr int LDA = 256, LDB = 256, LDC = 1024, NT = 8;
  __shared__ f16 lds[3][2][128][32];   // 48 KiB
  const int tid = threadIdx.x, wid = tid >> 6, lane = tid & 63;
  const int bid = blockIdx.x;
  const int m0 = ((bid & 7) * 32 + (bid >> 6)) * 128;
  const int n0 = ((bid >> 3) & 7) * 128;
  const int wr = (wid >> 1) * 64, wc = (wid & 1) * 64;

  const f16* srcA[2]; const f16* srcB[2];
#pragma unroll
  for (int q = 0; q < 2; ++q) {
    int s = (wid * 2 + q) * 64 + lane;
    int row = s >> 2, g = (s & 3) ^ ((row >> 1) & 3);
    srcA[q] = A + (size_t)(m0 + row) * LDA + g * 8;
    srcB[q] = Bw + (size_t)(n0 + row) * LDB + g * 8;
  }
  auto stage = [&](int buf, int kt) {
    f16* la = &lds[buf][0][0][0] + (wid * 2) * 512;
    f16* lb = &lds[buf][1][0][0] + (wid * 2) * 512;
#pragma unroll
    for (int q = 0; q < 2; ++q) {
      __builtin_amdgcn_global_load_lds(AS1(srcA[q] + kt * 32), AS3(la + q * 512), 16, 0, 0);
      __builtin_amdgcn_global_load_lds(AS1(srcB[q] + kt * 32), AS3(lb + q * 512), 16, 0, 0);
    }
  };
  const int r = lane & 15;
  const int cs = (((lane >> 4) ^ ((lane >> 1) & 3)) << 3);

  f32x4 acc[4][4] = {};
  stage(0, 0); stage(1, 1);
  asm volatile("s_waitcnt vmcnt(4)" ::: "memory");
  __syncthreads();
#pragma unroll
  for (int kt = 0; kt < NT; ++kt) {
    if (kt + 2 < NT) stage((kt + 2) % 3, kt + 2);
    f16(*At)[32] = lds[kt % 3][0];
    f16(*Bt)[32] = lds[kt % 3][1];
    f16x8 af[4], bf[4];
#pragma unroll
    for (int i = 0; i < 4; ++i) af[i] = *(const f16x8*)&At[wr + i * 16 + r][cs];
#pragma unroll
    for (int i = 0; i < 4; ++i) bf[i] = *(const f16x8*)&Bt[wc + i * 16 + r][cs];
#pragma unroll
    for (int mi = 0; mi < 4; ++mi)
#pragma unroll
      for (int ni = 0; ni < 4; ++ni)
        MFMA16(acc[mi][ni], af[mi], bf[ni]);
    if (kt + 1 < NT) {
      if (kt + 2 < NT) asm volatile("s_waitcnt vmcnt(4)" ::: "memory");
      else             asm volatile("s_waitcnt vmcnt(0)" ::: "memory");
      __syncthreads();
    }
  }

  __syncthreads();
  const bool sig = n0 < 512;
  f16* ep = &lds[0][0][0][0] + wid * 4096;
  const int rq = (lane >> 4) * 4;
#pragma unroll
  for (int ni = 0; ni < 4; ++ni) {
    float bv = bias[n0 + wc + ni * 16 + r];
    int cc = ni * 2 + (r >> 3);
#pragma unroll
    for (int mi = 0; mi < 4; ++mi) {
#pragma unroll
      for (int j = 0; j < 4; ++j) {
        int lrow = mi * 16 + rq + j;
        float v = acc[mi][ni][j] + bv;
        float av = sig ? sigmoid_fast(v) : tanh_fast(v);
        ep[lrow * 64 + ((cc ^ (lrow & 7)) << 3) + (r & 7)] = (f16)av;
      }
    }
  }
  asm volatile("s_waitcnt lgkmcnt(0)" ::: "memory");
  __builtin_amdgcn_sched_barrier(0);
#pragma unroll
  for (int t = 0; t < 8; ++t) {
    int idx = t * 64 + lane;
    int row = idx >> 3, c = idx & 7;
    f16x8 v = *(const f16x8*)(ep + row * 64 + ((c ^ (row & 7)) << 3));
    *(f16x8*)(Cout + (size_t)(m0 + wr + row) * LDC + n0 + wc + c * 8) = v;
  }
}

// ---------------- GEMM2 (v3 @ (256,3)): h@W1^T + b1 -> gelu -> f16 ----------------

__global__ __launch_bounds__(256, 3) void gemm2_a(
    const f16* __restrict__ A, const f16* __restrict__ Bw,
    const float* __restrict__ bias, f16* __restrict__ Cout) {
  constexpr int LDA = 1024, LDB = 512, LDC = 2048, NT = 16;
  __shared__ f16 lds[24576];   // 48 KiB -> 3 blk/CU
  const int tid = threadIdx.x, wid = tid >> 6, lane = tid & 63;
  const int lr = lane & 15;
  const int bid = blockIdx.x;
  const int m0 = ((bid & 7) * 8 + (bid >> 7)) * 256;
  const int n0 = ((bid >> 3) & 15) * 128;
  const int wr = (wid >> 1) * 128, wc = (wid & 1) * 64;

  const f16* srcA[4];
  const f16* srcB[2];
#pragma unroll
  for (int q = 0; q < 4; ++q) {
    int s = wid * 256 + q * 64 + lane;
    int row = s >> 2, g = (s & 3) ^ ((row >> 1) & 3);
    srcA[q] = A + (size_t)(m0 + row) * LDA + g * 8;
  }
#pragma unroll
  for (int q = 0; q < 2; ++q) {
    int s = wid * 128 + q * 64 + lane;
    int row = s >> 2, g = (s & 3) ^ ((row >> 1) & 3);
    srcB[q] = Bw + (size_t)(n0 + row) * LDB + g * 8;
  }
  auto stage = [&](int buf, int kt) {
#pragma unroll
    for (int q = 0; q < 4; ++q)
      __builtin_amdgcn_global_load_lds(AS1(srcA[q] + kt * 32),
          AS3(lds + buf * 8192 + wid * 2048 + q * 512), 16, 0, 0);
#pragma unroll
    for (int q = 0; q < 2; ++q)
      __builtin_amdgcn_global_load_lds(AS1(srcB[q] + kt * 32),
          AS3(lds + 16384 + buf * 4096 + wid * 1024 + q * 512), 16, 0, 0);
  };

  const int qsf = (((lane >> 4) ^ ((lr >> 1) & 3)) << 3);
  f32x4 acc[8][4] = {};
  stage(0, 0);
  for (int kt = 0; kt < NT; ++kt) {
    const int cur = kt & 1;
    __syncthreads();
    if (kt + 1 < NT) stage(cur ^ 1, kt + 1);
    f16x8 af[8], bf[4];
#pragma unroll
    for (int mi = 0; mi < 8; ++mi)
      af[mi] = *(const f16x8*)(lds + cur * 8192 + (wr + mi * 16 + lr) * 32 + qsf);
#pragma unroll
    for (int ni = 0; ni < 4; ++ni)
      bf[ni] = *(const f16x8*)(lds + 16384 + cur * 4096 + (wc + ni * 16 + lr) * 32 + qsf);
#pragma unroll
    for (int mi = 0; mi < 8; ++mi)
#pragma unroll
      for (int ni = 0; ni < 4; ++ni)
        MFMA16(acc[mi][ni], af[mi], bf[ni]);
  }

  __syncthreads();
  f16* ep = lds + wid * 4096;
  const int rq = (lane >> 4) * 4;
#pragma unroll
  for (int h = 0; h < 2; ++h) {
#pragma unroll
    for (int mi = 0; mi < 4; ++mi) {
#pragma unroll
      for (int ni = 0; ni < 4; ++ni) {
        float bv = bias[n0 + wc + ni * 16 + lr];
        int cc = ni * 2 + (lr >> 3);
#pragma unroll
        for (int j = 0; j < 4; ++j) {
          int lrow = mi * 16 + rq + j;
          float v = gelu_fast(acc[h * 4 + mi][ni][j] + bv);
          ep[lrow * 64 + ((cc ^ (lrow & 7)) << 3) + (lr & 7)] = (f16)v;
        }
      }
    }
    asm volatile("s_waitcnt lgkmcnt(0)" ::: "memory");
    __builtin_amdgcn_sched_barrier(0);
#pragma unroll
    for (int t = 0; t < 8; ++t) {
      int idx = t * 64 + lane;
      int row = idx >> 3, c = idx & 7;
      f16x8 v = *(const f16x8*)(ep + row * 64 + ((c ^ (row & 7)) << 3));
      *(f16x8*)(Cout + (size_t)(m0 + wr + h * 64 + row) * LDC + n0 + wc + c * 8) = v;
    }
    asm volatile("s_waitcnt lgkmcnt(0)" ::: "memory");
    __builtin_amdgcn_sched_barrier(0);
  }
}

// ---------------- GEMM3 (128x64 tile, grid 512 = 2 blk/CU): z@W2^T + b2 -> f32 ------

__global__ __launch_bounds__(256, 2) void gemm3_h(
    const f16* __restrict__ A, const f16* __restrict__ Bw,
    const float* __restrict__ bias, float* __restrict__ Cout) {
  constexpr int LDA = 2048, LDB = 2048, LDC = 256, NT = 32;
  __shared__ f16 lds[24576];   // A: buf*8192 + row*64 ; B: 16384 + buf*4096 + row*64
  const int tid = threadIdx.x, wid = tid >> 6, lane = tid & 63;
  const int bid = blockIdx.x;  // 512 = 8 xcd x 4 n x 16 m
  const int m0 = ((bid & 7) * 16 + (bid >> 5)) * 128;
  const int n0 = ((bid >> 3) & 3) * 64;
  const int wr = (wid >> 1) * 64, wc = (wid & 1) * 32;

  auto stage = [&](int buf, int kt) {
    const f16* ga = A + (size_t)m0 * LDA + kt * 64;
    const f16* gb = Bw + (size_t)n0 * LDB + kt * 64;
#pragma unroll
    for (int q = 0; q < 4; ++q) {
      int seg = wid * 4 + q;          // 0..15
      int s = seg * 64 + lane;
      int row = s >> 3, col = (s & 7) << 3;
      __builtin_amdgcn_global_load_lds(AS1(ga + (size_t)row * LDA + col),
                                       AS3(lds + buf * 8192 + seg * 512), 16, 0, 0);
    }
#pragma unroll
    for (int q = 0; q < 2; ++q) {
      int seg = wid * 2 + q;          // 0..7
      int s = seg * 64 + lane;
      int row = s >> 3, col = (s & 7) << 3;
      __builtin_amdgcn_global_load_lds(AS1(gb + (size_t)row * LDB + col),
                                       AS3(lds + 16384 + buf * 4096 + seg * 512), 16, 0, 0);
    }
  };

  f32x4 acc[4][2] = {};
  stage(0, 0);
  for (int kt = 0; kt < NT; ++kt) {
    __syncthreads();
    if (kt + 1 < NT) stage((kt + 1) & 1, kt + 1);
    const f16* At = lds + (kt & 1) * 8192;
    const f16* Bt = lds + 16384 + (kt & 1) * 4096;
    const int r = lane & 15, cg = (lane >> 4) << 3;
#pragma unroll
    for (int kk = 0; kk < 2; ++kk) {
      f16x8 af[4], bf[2];
#pragma unroll
      for (int i = 0; i < 4; ++i)
        af[i] = *(const f16x8*)(At + (wr + i * 16 + r) * 64 + kk * 32 + cg);
#pragma unroll
      for (int i = 0; i < 2; ++i)
        bf[i] = *(const f16x8*)(Bt + (wc + i * 16 + r) * 64 + kk * 32 + cg);
#pragma unroll
      for (int mi = 0; mi < 4; ++mi)
#pragma unroll
        for (int ni = 0; ni < 2; ++ni)
          MFMA16(acc[mi][ni], af[mi], bf[ni]);
    }
  }
  const int r = lane & 15, rq = (lane >> 4) * 4;
#pragma unroll
  for (int ni = 0; ni < 2; ++ni) {
    int col = n0 + wc + ni * 16 + r;
    float bv = bias[col];
#pragma unroll
    for (int mi = 0; mi < 4; ++mi) {
#pragma unroll
      for (int j = 0; j < 4; ++j) {
        int row = m0 + wr + mi * 16 + rq + j;
        Cout[(size_t)row * LDC + col] = acc[mi][ni][j] + bv;
      }
    }
  }
}

// ---------------- scan (3-pass, gates pre-activated; HBM roofline) ----------------

#define NCH 16384
#define NCHUNK 32
#define CLEN 64

__global__ void scan_p1(const f16* __restrict__ ab, float* __restrict__ cA,
                        float* __restrict__ cH) {
  int ch = blockIdx.x * 256 + threadIdx.x;
  int c = blockIdx.y;
  const f16* pg = ab + (size_t)(c * CLEN) * 32768 + (ch >> 9) * 1024 + (ch & 511);
  const f16* pi = pg + 512;
  float A = 1.f, Hl = 0.f;
  for (int t = 0; t < CLEN; ++t) {
    float g = (float)pg[0];
    float ii = (float)pi[0];
    Hl = fmaf(g, Hl - ii, ii);
    A *= g;
    pg += 32768; pi += 32768;
  }
  cA[c * NCH + ch] = A;
  cH[c * NCH + ch] = Hl;
}

__global__ void scan_p2(const float* __restrict__ cA, const float* __restrict__ cH,
                        float* __restrict__ st) {
  int ch = blockIdx.x * 256 + threadIdx.x;
  float h0 = 0.f;
  for (int c = 0; c < NCHUNK; ++c) {
    st[c * NCH + ch] = h0;
    h0 = cA[c * NCH + ch] * h0 + cH[c * NCH + ch];
  }
}

__global__ void scan_p3(f16* __restrict__ ab, const float* __restrict__ st) {
  int ch = blockIdx.x * 256 + threadIdx.x;
  int c = blockIdx.y;
  f16* pg = ab + (size_t)(c * CLEN) * 32768 + (ch >> 9) * 1024 + (ch & 511);
  const f16* pi = pg + 512;
  float hv = st[c * NCH + ch];
  for (int t = 0; t < CLEN; ++t) {
    float g = (float)pg[0];
    float ii = (float)pi[0];
    hv = fmaf(g, hv - ii, ii);
    pg[0] = (f16)hv;
    pg += 32768; pi += 32768;
  }
}

// ---------------- launch ----------------

extern "C" void kernel_launch(void* const* d_in, const int* in_sizes, int n_in,
                              void* d_out, int out_size, void* d_ws, size_t ws_size,
                              hipStream_t stream) {
  const float* x  = (const float*)d_in[0];
  const float* Wg = (const float*)d_in[1];
  const float* bg = (const float*)d_in[2];
  const float* Wi = (const float*)d_in[3];
  const float* bi = (const float*)d_in[4];
  const float* W1 = (const float*)d_in[5];
  const float* b1 = (const float*)d_in[6];
  const float* W2 = (const float*)d_in[7];
  const float* b2 = (const float*)d_in[8];
  float* out = (float*)d_out;

  char* ws = (char*)d_ws;
  f16*   wgi16 = (f16*)(ws + 0);            // 1024x256 f16
  f16*   w116  = (f16*)(ws + 524288);       // 2048x512 f16
  f16*   w216  = (f16*)(ws + 2621440);      // 256x2048 f16
  float* bgi   = (float*)(ws + 3670016);    // 1024 f32
  f16*   x16   = (f16*)(ws + 4194304);      // 65536x256 f16
  f16*   ab16  = (f16*)(ws + 37748736);     // 65536x1024 f16 (g|i, then h|i)
  float* cA    = (float*)(ws + 171966464);  // 32x16384 f32
  float* cH    = (float*)(ws + 174063616);
  float* st    = (float*)(ws + 176160768);
  f16*   z16   = (f16*)(ws + 178257920);    // 16384x2048 f16
  if (ws_size < 245366784) return;

  // prep
  cvt_w<<<896, 256, 0, stream>>>(Wg, Wi, W1, W2, wgi16, w116, w216);
  bias_cat_kernel<<<1, 1024, 0, stream>>>(bg, bi, bgi);
  cvt_kernel<<<8192, 256, 0, stream>>>(x, x16, 2097152);

  // GEMM1 halves
  gemm1_t2<<<2048, 256, 0, stream>>>(x16, wgi16, bgi, ab16);
  gemm1_t3<<<2048, 256, 0, stream>>>(x16 + (size_t)32768 * 256, wgi16, bgi,
                                     ab16 + (size_t)32768 * 1024);

  // scan
  scan_p1<<<dim3(64, NCHUNK), 256, 0, stream>>>(ab16, cA, cH);
  scan_p2<<<64, 256, 0, stream>>>(cA, cH, st);
  scan_p3<<<dim3(64, NCHUNK), 256, 0, stream>>>(ab16, st);

  // 4 T-slabs: GEMM2 (all gemm2_a) -> z16 ; GEMM3 (all gemm3_h) -> out
  for (int s = 0; s < 4; ++s) {
    const f16* hs = ab16 + (size_t)s * 16384 * 1024;
    gemm2_a<<<1024, 256, 0, stream>>>(hs, w116, b1, z16);
    gemm3_h<<<512, 256, 0, stream>>>(z16, w216, b2, out + (size_t)s * 16384 * 256);
  }
}